// Round 3
// baseline (143.677 us; speedup 1.0000x reference)
//
#include <hip/hip_runtime.h>
#include <hip/hip_bf16.h>
#include <math.h>

// FieldTypedProjector: per-token Fourier features -> per-kind 2-layer MLP (exact GELU)
//   out[t] = W2[k]^T gelu(W1[k]^T ff(v_t) + b1[k]) + b2[k] + kind_emb[k]
// R2: atomic-free bucketing (hist -> scan -> scatter; R1's 8-counter cache line
// serialized 2048 device atomics), LDS-staged coalesced weight pack, fproj with
// worklist grid (1032 vs 8192 blocks), Apack aliased into Hpack (LDS 41.5->33 KB,
// 3->4 blocks/CU), B1/epilogue prefetch, nontemporal out stores.

#define NK 8
#define DM 256
#define TMAX 65536     // N*S = 32*2048
#define NBLK 256       // T/256 histogram/scatter blocks
#define W1PK 16384     // per-kind packed W1 elements (64*256)
#define W2PK 65536     // per-kind packed W2 elements (256*256)
#define LDSTRIDE 262   // slab stride: 8*262 % 32 == 16 -> 2-way (free) on packed reads

typedef __attribute__((ext_vector_type(8))) short   s16x8;
typedef __attribute__((ext_vector_type(8))) __bf16  bf16x8;
typedef __attribute__((ext_vector_type(4))) float   f32x4;
typedef __attribute__((ext_vector_type(2))) float   f32x2;
typedef __attribute__((ext_vector_type(4))) int     i32x4;

// Static device scratch — rewritten every call (never touches d_ws).
__device__ int   g_counts[NK];
__device__ __align__(16) int g_blkcnt[NBLK][NK];
__device__ int   g_bucket[(size_t)NK * TMAX];
__device__ __align__(16) short g_W1p[(size_t)NK * W1PK];
__device__ __align__(16) short g_W2p[(size_t)NK * W2PK];

static __device__ __forceinline__ short f2bf(float f) {
    __hip_bfloat16 h = __float2bfloat16(f);
    return __builtin_bit_cast(short, h);
}

static __device__ __forceinline__ f32x4 mfma16(s16x8 a, s16x8 b, f32x4 c) {
    return __builtin_amdgcn_mfma_f32_16x16x32_bf16(
        __builtin_bit_cast(bf16x8, a), __builtin_bit_cast(bf16x8, b), c, 0, 0, 0);
}

// ---------------- kernel A: weight pack (LDS-staged) + per-block histograms ---
// bid <  64 : W2 slab, kind=bid>>3, ktile=bid&7  (32 rows x 256 cols)
// bid 64..79: W1 slab, kind=(bid-64)>>1, ktile=(bid-64)&1 (rows >=48 zero-pad)
// bid >= 80 : histogram block b=bid-80 over tokens [b*256, +256)
__global__ __launch_bounds__(256) void prep_kernel(const float* __restrict__ W1,
                                                   const float* __restrict__ W2,
                                                   const int* __restrict__ kinds, int T) {
    __shared__ float ld[32 * LDSTRIDE];
    __shared__ int wcnt[4][NK];
    const int tid = threadIdx.x;
    const int bid = blockIdx.x;
    if (bid < 80) {
        const int isW1 = (bid >= 64);
        int kind, kt;
        if (isW1) { kind = (bid - 64) >> 1; kt = (bid - 64) & 1; }
        else      { kind = bid >> 3;        kt = bid & 7; }
        // coalesced slab load: 8 float4 per thread
        #pragma unroll
        for (int i = 0; i < 8; ++i) {
            int f = tid + i * 256;            // float4 index within 32x256 slab
            int row = f >> 6, col = (f & 63) * 4;
            int kk = kt * 32 + row;
            f32x4 v = (f32x4){0.f, 0.f, 0.f, 0.f};
            if (isW1) {
                if (kk < 48) v = *(const f32x4*)(W1 + ((size_t)kind * 48 + kk) * DM + col);
            } else {
                v = *(const f32x4*)(W2 + ((size_t)kind * DM + kk) * DM + col);
            }
            float* dst = &ld[row * LDSTRIDE + col];
            *(f32x2*)dst       = (f32x2){v[0], v[1]};
            *(f32x2*)(dst + 2) = (f32x2){v[2], v[3]};
        }
        __syncthreads();
        // pack to B-frag order: group = (ktile*16 + ntile)*64 + lane, 8 elems each
        short* outp = isW1 ? (g_W1p + (size_t)kind * W1PK) : (g_W2p + (size_t)kind * W2PK);
        #pragma unroll
        for (int i = 0; i < 4; ++i) {
            int g = tid + i * 256;            // ntile*64 + lane
            int ntile = g >> 6, l = g & 63;
            int kk0 = (l >> 4) * 8, n = ntile * 16 + (l & 15);
            s16x8 v;
            #pragma unroll
            for (int j = 0; j < 8; ++j) v[j] = f2bf(ld[(kk0 + j) * LDSTRIDE + n]);
            *(s16x8*)(outp + ((size_t)(kt * 16 + ntile) * 64 + l) * 8) = v;
        }
    } else {
        const int b = bid - 80;
        const int wave = tid >> 6, lane = tid & 63;
        int t = b * 256 + tid;
        int k = (t < T) ? kinds[t] : -1;
        #pragma unroll
        for (int kk = 0; kk < NK; ++kk) {
            unsigned long long m = __ballot(k == kk);
            if (lane == 0) wcnt[wave][kk] = __popcll(m);
        }
        __syncthreads();
        if (tid < NK) {
            int s = 0;
            #pragma unroll
            for (int w = 0; w < 4; ++w) s += wcnt[w][tid];
            g_blkcnt[b][tid] = s;
        }
    }
}

// ---------------- kernel B: exclusive scan over block counts + scatter --------
__global__ __launch_bounds__(256) void scatter_kernel(const int* __restrict__ kinds, int T) {
    __shared__ int cnt_s[NBLK * NK];   // 8 KB: all block histograms
    __shared__ int wcnt[4][NK];
    __shared__ int base_s[NK];
    const int tid = threadIdx.x, wave = tid >> 6, lane = tid & 63;
    const int b = blockIdx.x;
    {
        const i32x4* src = (const i32x4*)&g_blkcnt[0][0];
        i32x4* dst = (i32x4*)cnt_s;
        dst[tid]       = src[tid];
        dst[tid + 256] = src[tid + 256];
    }
    int t = b * 256 + tid;
    int k = (t < T) ? kinds[t] : -1;
    int rank = 0;
    #pragma unroll
    for (int kk = 0; kk < NK; ++kk) {
        unsigned long long m = __ballot(k == kk);
        if (lane == 0) wcnt[wave][kk] = __popcll(m);
        if (k == kk) rank = __popcll(m & ((1ull << lane) - 1ull));
    }
    __syncthreads();
    if (tid < NK) {
        int s = 0;
        for (int bb = 0; bb < NBLK; ++bb) {
            if (bb == b) base_s[tid] = s;
            s += cnt_s[bb * NK + tid];
        }
        if (b == 0) g_counts[tid] = s;
        int ws = 0;
        #pragma unroll
        for (int w = 0; w < 4; ++w) { int c = wcnt[w][tid]; wcnt[w][tid] = ws; ws += c; }
    }
    __syncthreads();
    if (k >= 0)
        g_bucket[(size_t)k * T + base_s[k] + wcnt[wave][k] + rank] = t;
}

// ---------------- kernel C: fused MLP, 64-token tile of one kind --------------
__global__ __launch_bounds__(256, 4) void fproj_gemm(
    const float* __restrict__ values, const float* __restrict__ Bmat,
    const float* __restrict__ kind_emb, const float* __restrict__ b1,
    const float* __restrict__ b2, float* __restrict__ out, int T)
{
    // worklist mapping: block -> (kind, tile)
    int cnts[NK];
    #pragma unroll
    for (int i = 0; i < NK; ++i) cnts[i] = g_counts[i];
    const int bid = blockIdx.x;
    int k = -1, m0 = 0, cum = 0, cnt = 0;
    #pragma unroll
    for (int kk = 0; kk < NK; ++kk) {
        int tk = (cnts[kk] + 63) >> 6;
        if (k < 0 && bid < cum + tk) { k = kk; m0 = (bid - cum) * 64; cnt = cnts[kk]; }
        cum += tk;
    }
    if (k < 0) return;
    const int valid = min(64, cnt - m0);

    __shared__ short Hpack[16384];     // h 64x256 A-frag order; first 8KB doubles as Apack
    __shared__ int   toks[64];
    __shared__ float vals[64];
    short* Apack = Hpack;

    const int tid  = threadIdx.x;
    const int wave = tid >> 6;
    const int lane = tid & 63;
    const int quad = lane >> 4;
    const int cl   = lane & 15;

    // prefetch B1 frags (global, independent of LDS phases)
    const s16x8* B1p = (const s16x8*)(g_W1p + (size_t)k * W1PK);
    s16x8 b1f[2][4];
    #pragma unroll
    for (int kt = 0; kt < 2; ++kt)
        #pragma unroll
        for (int nt = 0; nt < 4; ++nt)
            b1f[kt][nt] = B1p[(kt * 16 + wave * 4 + nt) * 64 + lane];

    if (tid < 64) {
        int t = -1; float v = 0.0f;
        if (tid < valid) { t = g_bucket[(size_t)k * T + m0 + tid]; v = values[t]; }
        toks[tid] = t; vals[tid] = v;
    }
    __syncthreads();

    // Fourier features -> Apack (A-frag layout): kk<24: sin, kk<48: cos, else 0
    for (int idx = tid; idx < 4096; idx += 256) {
        int m = idx >> 6, kk = idx & 63;
        float f = 0.0f;
        if (kk < 48) {
            int b = (kk < 24) ? kk : kk - 24;
            float y = 6.283185307179586f * vals[m] * Bmat[b];
            f = (kk < 24) ? __sinf(y) : __cosf(y);
        }
        int mt = m >> 4, kt = kk >> 5, q = (kk >> 3) & 3, j = kk & 7;
        int l = (m & 15) | (q << 4);
        Apack[((kt * 4 + mt) << 9) + (l << 3) + j] = f2bf(f);
    }
    __syncthreads();

    // ---- GEMM1: [64 x 64] x [64 x 256], wave covers cols [wave*64, +64)
    f32x4 acc[4][4];
    #pragma unroll
    for (int mt = 0; mt < 4; ++mt)
        #pragma unroll
        for (int nt = 0; nt < 4; ++nt) acc[mt][nt] = (f32x4){0.f, 0.f, 0.f, 0.f};

    const s16x8* Ap = (const s16x8*)Apack;
    #pragma unroll
    for (int kt = 0; kt < 2; ++kt) {
        s16x8 a[4];
        #pragma unroll
        for (int mt = 0; mt < 4; ++mt) a[mt] = Ap[(kt * 4 + mt) * 64 + lane];
        #pragma unroll
        for (int mt = 0; mt < 4; ++mt)
            #pragma unroll
            for (int nt = 0; nt < 4; ++nt) acc[mt][nt] = mfma16(a[mt], b1f[kt][nt], acc[mt][nt]);
    }
    __syncthreads();   // all Apack reads done before Hpack overwrite (aliased)

    // ---- bias + exact GELU -> Hpack (A-frag layout)
    #pragma unroll
    for (int nt = 0; nt < 4; ++nt) {
        int c = wave * 64 + nt * 16 + cl;
        float bias = b1[k * DM + c];
        int kt2 = c >> 5, q2 = (c >> 3) & 3, j2 = c & 7;
        #pragma unroll
        for (int mt = 0; mt < 4; ++mt)
            #pragma unroll
            for (int r4 = 0; r4 < 4; ++r4) {
                int r = mt * 16 + quad * 4 + r4;
                float x = acc[mt][nt][r4] + bias;
                float h = 0.5f * x * (1.0f + erff(x * 0.7071067811865476f));
                int l2 = (r & 15) | (q2 << 4);
                Hpack[((kt2 * 4 + (r >> 4)) << 9) + (l2 << 3) + j2] = f2bf(h);
            }
    }
    __syncthreads();

    // epilogue constants prefetch (independent of GEMM2)
    float addc[4];
    #pragma unroll
    for (int nt = 0; nt < 4; ++nt) {
        int c = wave * 64 + nt * 16 + cl;
        addc[nt] = b2[k * DM + c] + kind_emb[k * DM + c];
    }

    // ---- GEMM2: [64 x 256] x [256 x 256], wave covers cols [wave*64, +64)
    f32x4 acc2[4][4];
    #pragma unroll
    for (int mt = 0; mt < 4; ++mt)
        #pragma unroll
        for (int nt = 0; nt < 4; ++nt) acc2[mt][nt] = (f32x4){0.f, 0.f, 0.f, 0.f};

    const s16x8* Hp  = (const s16x8*)Hpack;
    const s16x8* B2p = (const s16x8*)(g_W2p + (size_t)k * W2PK);
    #pragma unroll
    for (int kt = 0; kt < 8; ++kt) {
        s16x8 a[4], b[4];
        #pragma unroll
        for (int mt = 0; mt < 4; ++mt) a[mt] = Hp[(kt * 4 + mt) * 64 + lane];
        #pragma unroll
        for (int nt = 0; nt < 4; ++nt) b[nt] = B2p[(kt * 16 + wave * 4 + nt) * 64 + lane];
        #pragma unroll
        for (int mt = 0; mt < 4; ++mt)
            #pragma unroll
            for (int nt = 0; nt < 4; ++nt) acc2[mt][nt] = mfma16(a[mt], b[nt], acc2[mt][nt]);
    }

    // ---- epilogue: + b2 + kind_emb, scatter rows to out (nontemporal)
    #pragma unroll
    for (int nt = 0; nt < 4; ++nt) {
        int c = wave * 64 + nt * 16 + cl;
        #pragma unroll
        for (int mt = 0; mt < 4; ++mt)
            #pragma unroll
            for (int r4 = 0; r4 < 4; ++r4) {
                int r = mt * 16 + quad * 4 + r4;
                if (r < valid)
                    __builtin_nontemporal_store(acc2[mt][nt][r4] + addc[nt],
                                                out + (size_t)toks[r] * DM + c);
            }
    }
}

extern "C" void kernel_launch(void* const* d_in, const int* in_sizes, int n_in,
                              void* d_out, int out_size, void* d_ws, size_t ws_size,
                              hipStream_t stream) {
    const float* values   = (const float*)d_in[0];
    const int*   kinds    = (const int*)  d_in[1];
    const float* Bmat     = (const float*)d_in[2];
    const float* kind_emb = (const float*)d_in[3];
    const float* W1       = (const float*)d_in[4];
    const float* b1       = (const float*)d_in[5];
    const float* W2       = (const float*)d_in[6];
    const float* b2       = (const float*)d_in[7];
    float* out = (float*)d_out;
    const int T = in_sizes[0];   // 65536

    prep_kernel<<<dim3(80 + NBLK), dim3(256), 0, stream>>>(W1, W2, kinds, T);
    scatter_kernel<<<dim3(NBLK), dim3(256), 0, stream>>>(kinds, T);
    fproj_gemm<<<dim3(T / 64 + NK), dim3(256), 0, stream>>>(values, Bmat, kind_emb,
                                                            b1, b2, out, T);
}

// Round 4
// 127.894 us; speedup vs baseline: 1.1234x; 1.1234x over previous
//
#include <hip/hip_runtime.h>
#include <hip/hip_bf16.h>
#include <math.h>

// FieldTypedProjector: per-token Fourier features -> per-kind 2-layer MLP (exact GELU)
//   out[t] = W2[k]^T gelu(W1[k]^T ff(v_t) + b1[k]) + b2[k] + kind_emb[k]
// R3 -> R4: fproj rework. M=32 tiles (2056 blocks, 8/CU vs 1032 = grid-limited 4/CU),
// LDS 33.3 -> 16.5 KB, tanh-form GELU (branch-free, ~9 VALU vs erff's ~25+),
// B2 fragment software pipeline, toks/vals LDS arrays dropped (L1-hot reloads).

#define NK 8
#define DM 256
#define TMAX 65536     // N*S = 32*2048
#define NBLK 256       // T/256 histogram/scatter blocks
#define W1PK 16384     // per-kind packed W1 elements (64*256)
#define W2PK 65536     // per-kind packed W2 elements (256*256)
#define LDSTRIDE 262   // slab stride: 8*262 % 32 == 16 -> 2-way (free) on packed reads

typedef __attribute__((ext_vector_type(8))) short   s16x8;
typedef __attribute__((ext_vector_type(8))) __bf16  bf16x8;
typedef __attribute__((ext_vector_type(4))) float   f32x4;
typedef __attribute__((ext_vector_type(2))) float   f32x2;
typedef __attribute__((ext_vector_type(4))) int     i32x4;

// Static device scratch — rewritten every call (never touches d_ws).
__device__ int   g_counts[NK];
__device__ __align__(16) int g_blkcnt[NBLK][NK];
__device__ int   g_bucket[(size_t)NK * TMAX];
__device__ __align__(16) short g_W1p[(size_t)NK * W1PK];
__device__ __align__(16) short g_W2p[(size_t)NK * W2PK];

static __device__ __forceinline__ short f2bf(float f) {
    __hip_bfloat16 h = __float2bfloat16(f);
    return __builtin_bit_cast(short, h);
}

static __device__ __forceinline__ f32x4 mfma16(s16x8 a, s16x8 b, f32x4 c) {
    return __builtin_amdgcn_mfma_f32_16x16x32_bf16(
        __builtin_bit_cast(bf16x8, a), __builtin_bit_cast(bf16x8, b), c, 0, 0, 0);
}

// tanh-form GELU: x*sigmoid(1.59577(x+0.044715x^3)); |err| vs exact erf ~3e-4
static __device__ __forceinline__ float gelu_fast(float x) {
    float t1 = x * x;
    float m  = fmaf(0.0713548162726f, t1, 1.59576912161f);   // 2*0.7978845608*(1, 0.044715)
    float z  = m * x;
    float e  = __expf(-z);
    return x * __frcp_rn(1.0f + e);
}

// ---------------- kernel A: weight pack (LDS-staged) + per-block histograms ---
__global__ __launch_bounds__(256) void prep_kernel(const float* __restrict__ W1,
                                                   const float* __restrict__ W2,
                                                   const int* __restrict__ kinds, int T) {
    __shared__ float ld[32 * LDSTRIDE];
    __shared__ int wcnt[4][NK];
    const int tid = threadIdx.x;
    const int bid = blockIdx.x;
    if (bid < 80) {
        const int isW1 = (bid >= 64);
        int kind, kt;
        if (isW1) { kind = (bid - 64) >> 1; kt = (bid - 64) & 1; }
        else      { kind = bid >> 3;        kt = bid & 7; }
        #pragma unroll
        for (int i = 0; i < 8; ++i) {
            int f = tid + i * 256;
            int row = f >> 6, col = (f & 63) * 4;
            int kk = kt * 32 + row;
            f32x4 v = (f32x4){0.f, 0.f, 0.f, 0.f};
            if (isW1) {
                if (kk < 48) v = *(const f32x4*)(W1 + ((size_t)kind * 48 + kk) * DM + col);
            } else {
                v = *(const f32x4*)(W2 + ((size_t)kind * DM + kk) * DM + col);
            }
            float* dst = &ld[row * LDSTRIDE + col];
            *(f32x2*)dst       = (f32x2){v[0], v[1]};
            *(f32x2*)(dst + 2) = (f32x2){v[2], v[3]};
        }
        __syncthreads();
        short* outp = isW1 ? (g_W1p + (size_t)kind * W1PK) : (g_W2p + (size_t)kind * W2PK);
        #pragma unroll
        for (int i = 0; i < 4; ++i) {
            int g = tid + i * 256;
            int ntile = g >> 6, l = g & 63;
            int kk0 = (l >> 4) * 8, n = ntile * 16 + (l & 15);
            s16x8 v;
            #pragma unroll
            for (int j = 0; j < 8; ++j) v[j] = f2bf(ld[(kk0 + j) * LDSTRIDE + n]);
            *(s16x8*)(outp + ((size_t)(kt * 16 + ntile) * 64 + l) * 8) = v;
        }
    } else {
        const int b = bid - 80;
        const int wave = tid >> 6, lane = tid & 63;
        int t = b * 256 + tid;
        int k = (t < T) ? kinds[t] : -1;
        #pragma unroll
        for (int kk = 0; kk < NK; ++kk) {
            unsigned long long m = __ballot(k == kk);
            if (lane == 0) wcnt[wave][kk] = __popcll(m);
        }
        __syncthreads();
        if (tid < NK) {
            int s = 0;
            #pragma unroll
            for (int w = 0; w < 4; ++w) s += wcnt[w][tid];
            g_blkcnt[b][tid] = s;
        }
    }
}

// ---------------- kernel B: exclusive scan over block counts + scatter --------
__global__ __launch_bounds__(256) void scatter_kernel(const int* __restrict__ kinds, int T) {
    __shared__ int cnt_s[NBLK * NK];
    __shared__ int wcnt[4][NK];
    __shared__ int base_s[NK];
    const int tid = threadIdx.x, wave = tid >> 6, lane = tid & 63;
    const int b = blockIdx.x;
    {
        const i32x4* src = (const i32x4*)&g_blkcnt[0][0];
        i32x4* dst = (i32x4*)cnt_s;
        dst[tid]       = src[tid];
        dst[tid + 256] = src[tid + 256];
    }
    int t = b * 256 + tid;
    int k = (t < T) ? kinds[t] : -1;
    int rank = 0;
    #pragma unroll
    for (int kk = 0; kk < NK; ++kk) {
        unsigned long long m = __ballot(k == kk);
        if (lane == 0) wcnt[wave][kk] = __popcll(m);
        if (k == kk) rank = __popcll(m & ((1ull << lane) - 1ull));
    }
    __syncthreads();
    if (tid < NK) {
        int s = 0;
        for (int bb = 0; bb < NBLK; ++bb) {
            if (bb == b) base_s[tid] = s;
            s += cnt_s[bb * NK + tid];
        }
        if (b == 0) g_counts[tid] = s;
        int ws = 0;
        #pragma unroll
        for (int w = 0; w < 4; ++w) { int c = wcnt[w][tid]; wcnt[w][tid] = ws; ws += c; }
    }
    __syncthreads();
    if (k >= 0)
        g_bucket[(size_t)k * T + base_s[k] + wcnt[wave][k] + rank] = t;
}

// ---------------- kernel C: fused MLP, 32-token tile of one kind --------------
__global__ __launch_bounds__(256, 4) void fproj_gemm(
    const float* __restrict__ values, const float* __restrict__ Bmat,
    const float* __restrict__ kind_emb, const float* __restrict__ b1,
    const float* __restrict__ b2, float* __restrict__ out, int T)
{
    // worklist mapping: block -> (kind, 32-token tile)
    int cnts[NK];
    #pragma unroll
    for (int i = 0; i < NK; ++i) cnts[i] = g_counts[i];
    const int bid = blockIdx.x;
    int k = -1, m0 = 0, cum = 0, cnt = 0;
    #pragma unroll
    for (int kk = 0; kk < NK; ++kk) {
        int tk = (cnts[kk] + 31) >> 5;
        if (k < 0 && bid < cum + tk) { k = kk; m0 = (bid - cum) * 32; cnt = cnts[kk]; }
        cum += tk;
    }
    if (k < 0) return;
    const int valid = min(32, cnt - m0);
    const int* buck = g_bucket + (size_t)k * T + m0;

    __shared__ short Hpack[8192];   // h 32x256 A-frag order (8 kt x 2 mt); first 4KB = Apack
    short* Apack = Hpack;

    const int tid  = threadIdx.x;
    const int wave = tid >> 6;
    const int lane = tid & 63;
    const int quad = lane >> 4;
    const int cl   = lane & 15;

    // prefetch B1 frags (global, independent of LDS phases)
    const s16x8* B1p = (const s16x8*)(g_W1p + (size_t)k * W1PK);
    s16x8 b1f[2][4];
    #pragma unroll
    for (int kt = 0; kt < 2; ++kt)
        #pragma unroll
        for (int nt = 0; nt < 4; ++nt)
            b1f[kt][nt] = B1p[(kt * 16 + wave * 4 + nt) * 64 + lane];

    // Fourier features -> Apack (A-frag layout): kk<24: sin, kk<48: cos, else 0
    #pragma unroll
    for (int i = 0; i < 8; ++i) {
        int idx = tid + i * 256;            // 32 rows x 64 kk
        int m = idx >> 6, kk = idx & 63;
        float f = 0.0f;
        if (kk < 48) {
            float v = 0.0f;
            if (m < valid) v = values[buck[m]];
            int b = (kk < 24) ? kk : kk - 24;
            float y = 6.283185307179586f * v * Bmat[b];
            f = (kk < 24) ? __sinf(y) : __cosf(y);
        }
        int mt = m >> 4, kt = kk >> 5, q = (kk >> 3) & 3, j = kk & 7;
        int l = (m & 15) | (q << 4);
        Apack[((kt * 2 + mt) << 9) + (l << 3) + j] = f2bf(f);
    }
    __syncthreads();

    // ---- GEMM1: [32 x 64] x [64 x 256], wave covers cols [wave*64, +64)
    f32x4 acc[2][4];
    #pragma unroll
    for (int mt = 0; mt < 2; ++mt)
        #pragma unroll
        for (int nt = 0; nt < 4; ++nt) acc[mt][nt] = (f32x4){0.f, 0.f, 0.f, 0.f};

    const s16x8* Ap = (const s16x8*)Apack;
    #pragma unroll
    for (int kt = 0; kt < 2; ++kt) {
        s16x8 a[2];
        #pragma unroll
        for (int mt = 0; mt < 2; ++mt) a[mt] = Ap[(kt * 2 + mt) * 64 + lane];
        #pragma unroll
        for (int mt = 0; mt < 2; ++mt)
            #pragma unroll
            for (int nt = 0; nt < 4; ++nt) acc[mt][nt] = mfma16(a[mt], b1f[kt][nt], acc[mt][nt]);
    }
    __syncthreads();   // Apack reads done before Hpack overwrite (aliased)

    // ---- bias + GELU -> Hpack (A-frag layout)
    #pragma unroll
    for (int nt = 0; nt < 4; ++nt) {
        int c = wave * 64 + nt * 16 + cl;
        float bias = b1[k * DM + c];
        int kt2 = c >> 5, q2 = (c >> 3) & 3, j2 = c & 7;
        #pragma unroll
        for (int mt = 0; mt < 2; ++mt)
            #pragma unroll
            for (int r4 = 0; r4 < 4; ++r4) {
                int r = mt * 16 + quad * 4 + r4;
                float h = gelu_fast(acc[mt][nt][r4] + bias);
                int l2 = (r & 15) | (q2 << 4);
                Hpack[((kt2 * 2 + mt) << 9) + (l2 << 3) + j2] = f2bf(h);
            }
    }
    __syncthreads();

    // epilogue constants prefetch (independent of GEMM2)
    float addc[4];
    #pragma unroll
    for (int nt = 0; nt < 4; ++nt) {
        int c = wave * 64 + nt * 16 + cl;
        addc[nt] = b2[k * DM + c] + kind_emb[k * DM + c];
    }

    // ---- GEMM2: [32 x 256] x [256 x 256], B-frags software-pipelined
    f32x4 acc2[2][4];
    #pragma unroll
    for (int mt = 0; mt < 2; ++mt)
        #pragma unroll
        for (int nt = 0; nt < 4; ++nt) acc2[mt][nt] = (f32x4){0.f, 0.f, 0.f, 0.f};

    const s16x8* Hp  = (const s16x8*)Hpack;
    const s16x8* B2p = (const s16x8*)(g_W2p + (size_t)k * W2PK);
    s16x8 bcur[4], bnxt[4];
    #pragma unroll
    for (int nt = 0; nt < 4; ++nt) bcur[nt] = B2p[(wave * 4 + nt) * 64 + lane];
    #pragma unroll
    for (int kt = 0; kt < 8; ++kt) {
        if (kt < 7) {
            #pragma unroll
            for (int nt = 0; nt < 4; ++nt)
                bnxt[nt] = B2p[((kt + 1) * 16 + wave * 4 + nt) * 64 + lane];
        }
        s16x8 a[2];
        #pragma unroll
        for (int mt = 0; mt < 2; ++mt) a[mt] = Hp[(kt * 2 + mt) * 64 + lane];
        #pragma unroll
        for (int mt = 0; mt < 2; ++mt)
            #pragma unroll
            for (int nt = 0; nt < 4; ++nt) acc2[mt][nt] = mfma16(a[mt], bcur[nt], acc2[mt][nt]);
        #pragma unroll
        for (int nt = 0; nt < 4; ++nt) bcur[nt] = bnxt[nt];
    }

    // ---- epilogue: + b2 + kind_emb, scatter rows to out (nontemporal)
    #pragma unroll
    for (int mt = 0; mt < 2; ++mt)
        #pragma unroll
        for (int r4 = 0; r4 < 4; ++r4) {
            int r = mt * 16 + quad * 4 + r4;
            if (r < valid) {
                size_t row = (size_t)buck[r] * DM;
                #pragma unroll
                for (int nt = 0; nt < 4; ++nt) {
                    int c = wave * 64 + nt * 16 + cl;
                    __builtin_nontemporal_store(acc2[mt][nt][r4] + addc[nt], out + row + c);
                }
            }
        }
}

extern "C" void kernel_launch(void* const* d_in, const int* in_sizes, int n_in,
                              void* d_out, int out_size, void* d_ws, size_t ws_size,
                              hipStream_t stream) {
    const float* values   = (const float*)d_in[0];
    const int*   kinds    = (const int*)  d_in[1];
    const float* Bmat     = (const float*)d_in[2];
    const float* kind_emb = (const float*)d_in[3];
    const float* W1       = (const float*)d_in[4];
    const float* b1       = (const float*)d_in[5];
    const float* W2       = (const float*)d_in[6];
    const float* b2       = (const float*)d_in[7];
    float* out = (float*)d_out;
    const int T = in_sizes[0];   // 65536

    prep_kernel<<<dim3(80 + NBLK), dim3(256), 0, stream>>>(W1, W2, kinds, T);
    scatter_kernel<<<dim3(NBLK), dim3(256), 0, stream>>>(kinds, T);
    fproj_gemm<<<dim3(T / 32 + NK), dim3(256), 0, stream>>>(values, Bmat, kind_emb,
                                                            b1, b2, out, T);
}

// Round 5
// 122.640 us; speedup vs baseline: 1.1715x; 1.0428x over previous
//
#include <hip/hip_runtime.h>
#include <hip/hip_bf16.h>
#include <math.h>

// FieldTypedProjector: per-token Fourier features -> per-kind 2-layer MLP (exact GELU)
//   out[t] = W2[k]^T gelu(W1[k]^T ff(v_t) + b1[k]) + b2[k] + kind_emb[k]
// R5: M=16 tiles (4104 blocks = 16/CU supply vs 8 resident -> replacement stream),
// FF built directly in MFMA A-frag registers (no Apack LDS, 1 barrier instead of 3,
// raw v_sin/v_cos in revolutions), acc register footprint halved (AGPR occupancy cap
// was the hidden limiter: VGPR counter said 44 but acc+prefetch hoards pushed unified
// file >100 -> 3 waves/SIMD). Scatter scan parallelized (256 serial iters -> ~45).

#define NK 8
#define DM 256
#define TMAX 65536     // N*S = 32*2048
#define NBLK 256       // T/256 histogram/scatter blocks
#define W1PK 16384     // per-kind packed W1 elements (64*256)
#define W2PK 65536     // per-kind packed W2 elements (256*256)
#define LDSTRIDE 262   // prep slab stride

typedef __attribute__((ext_vector_type(8))) short   s16x8;
typedef __attribute__((ext_vector_type(8))) __bf16  bf16x8;
typedef __attribute__((ext_vector_type(4))) float   f32x4;
typedef __attribute__((ext_vector_type(2))) float   f32x2;
typedef __attribute__((ext_vector_type(4))) int     i32x4;

// Static device scratch — rewritten every call (never touches d_ws).
__device__ int   g_counts[NK];
__device__ __align__(16) int g_blkcnt[NBLK][NK];
__device__ int   g_bucket[(size_t)NK * TMAX];
__device__ __align__(16) short g_W1p[(size_t)NK * W1PK];
__device__ __align__(16) short g_W2p[(size_t)NK * W2PK];

static __device__ __forceinline__ short f2bf(float f) {
    __hip_bfloat16 h = __float2bfloat16(f);
    return __builtin_bit_cast(short, h);
}

// cheap round-to-nearest bf16 truncation (error <= 1 ulp bf16; margin is ~3x)
static __device__ __forceinline__ short pkbf(float f) {
    unsigned u = __builtin_bit_cast(unsigned, f);
    return (short)((u + 0x8000u) >> 16);
}

static __device__ __forceinline__ f32x4 mfma16(s16x8 a, s16x8 b, f32x4 c) {
    return __builtin_amdgcn_mfma_f32_16x16x32_bf16(
        __builtin_bit_cast(bf16x8, a), __builtin_bit_cast(bf16x8, b), c, 0, 0, 0);
}

// tanh-form GELU: x*sigmoid(1.59577(x+0.044715x^3)); |err| vs exact erf ~3e-4
static __device__ __forceinline__ float gelu_fast(float x) {
    float t1 = x * x;
    float m  = fmaf(0.0713548162726f, t1, 1.59576912161f);
    float z  = m * x;
    float e  = __expf(-z);
    return x * __frcp_rn(1.0f + e);
}

// ---------------- kernel A: weight pack (LDS-staged) + per-block histograms ---
__global__ __launch_bounds__(256) void prep_kernel(const float* __restrict__ W1,
                                                   const float* __restrict__ W2,
                                                   const int* __restrict__ kinds, int T) {
    __shared__ float ld[32 * LDSTRIDE];
    __shared__ int wcnt[4][NK];
    const int tid = threadIdx.x;
    const int bid = blockIdx.x;
    if (bid < 80) {
        const int isW1 = (bid >= 64);
        int kind, kt;
        if (isW1) { kind = (bid - 64) >> 1; kt = (bid - 64) & 1; }
        else      { kind = bid >> 3;        kt = bid & 7; }
        #pragma unroll
        for (int i = 0; i < 8; ++i) {
            int f = tid + i * 256;
            int row = f >> 6, col = (f & 63) * 4;
            int kk = kt * 32 + row;
            f32x4 v = (f32x4){0.f, 0.f, 0.f, 0.f};
            if (isW1) {
                if (kk < 48) v = *(const f32x4*)(W1 + ((size_t)kind * 48 + kk) * DM + col);
            } else {
                v = *(const f32x4*)(W2 + ((size_t)kind * DM + kk) * DM + col);
            }
            float* dst = &ld[row * LDSTRIDE + col];
            *(f32x2*)dst       = (f32x2){v[0], v[1]};
            *(f32x2*)(dst + 2) = (f32x2){v[2], v[3]};
        }
        __syncthreads();
        short* outp = isW1 ? (g_W1p + (size_t)kind * W1PK) : (g_W2p + (size_t)kind * W2PK);
        #pragma unroll
        for (int i = 0; i < 4; ++i) {
            int g = tid + i * 256;
            int ntile = g >> 6, l = g & 63;
            int kk0 = (l >> 4) * 8, n = ntile * 16 + (l & 15);
            s16x8 v;
            #pragma unroll
            for (int j = 0; j < 8; ++j) v[j] = f2bf(ld[(kk0 + j) * LDSTRIDE + n]);
            *(s16x8*)(outp + ((size_t)(kt * 16 + ntile) * 64 + l) * 8) = v;
        }
    } else {
        const int b = bid - 80;
        const int wave = tid >> 6, lane = tid & 63;
        int t = b * 256 + tid;
        int k = (t < T) ? kinds[t] : -1;
        #pragma unroll
        for (int kk = 0; kk < NK; ++kk) {
            unsigned long long m = __ballot(k == kk);
            if (lane == 0) wcnt[wave][kk] = __popcll(m);
        }
        __syncthreads();
        if (tid < NK) {
            int s = 0;
            #pragma unroll
            for (int w = 0; w < 4; ++w) s += wcnt[w][tid];
            g_blkcnt[b][tid] = s;
        }
    }
}

// ---------------- kernel B: two-level scan over block counts + scatter --------
__global__ __launch_bounds__(256) void scatter_kernel(const int* __restrict__ kinds, int T) {
    __shared__ int cnt_s[NBLK * NK];      // all block histograms (8 KB)
    __shared__ int chunksum[32][NK];      // 32 chunks of 8 blocks
    __shared__ int chunkpref[32][NK];
    __shared__ int wcnt[4][NK];
    __shared__ int base_s[NK];
    const int tid = threadIdx.x, wave = tid >> 6, lane = tid & 63;
    const int b = blockIdx.x;
    {
        const i32x4* src = (const i32x4*)&g_blkcnt[0][0];
        i32x4* dst = (i32x4*)cnt_s;
        dst[tid]       = src[tid];
        dst[tid + 256] = src[tid + 256];
    }
    int t = b * 256 + tid;
    int k = (t < T) ? kinds[t] : -1;
    int rank = 0;
    #pragma unroll
    for (int kk = 0; kk < NK; ++kk) {
        unsigned long long m = __ballot(k == kk);
        if (lane == 0) wcnt[wave][kk] = __popcll(m);
        if (k == kk) rank = __popcll(m & ((1ull << lane) - 1ull));
    }
    __syncthreads();
    {   // level 1: per-chunk sums (all 256 threads)
        int kk = tid & 7, ch = tid >> 3;
        int s = 0;
        #pragma unroll
        for (int i = 0; i < 8; ++i) s += cnt_s[(ch * 8 + i) * NK + kk];
        chunksum[ch][kk] = s;
    }
    __syncthreads();
    if (tid < NK) {   // level 2: serial over 32 chunks + <=8 within-chunk
        int s = 0;
        #pragma unroll
        for (int ch = 0; ch < 32; ++ch) { chunkpref[ch][tid] = s; s += chunksum[ch][tid]; }
        if (b == 0) g_counts[tid] = s;
        int ch = b >> 3;
        int s2 = chunkpref[ch][tid];
        for (int bb = ch * 8; bb < b; ++bb) s2 += cnt_s[bb * NK + tid];
        base_s[tid] = s2;
        int ws = 0;
        #pragma unroll
        for (int w = 0; w < 4; ++w) { int c = wcnt[w][tid]; wcnt[w][tid] = ws; ws += c; }
    }
    __syncthreads();
    if (k >= 0)
        g_bucket[(size_t)k * T + base_s[k] + wcnt[wave][k] + rank] = t;
}

// ---------------- kernel C: fused MLP, 16-token tile of one kind --------------
__global__ __launch_bounds__(256, 4) void fproj_gemm(
    const float* __restrict__ values, const float* __restrict__ Bmat,
    const float* __restrict__ kind_emb, const float* __restrict__ b1,
    const float* __restrict__ b2, float* __restrict__ out, int T)
{
    // worklist mapping: block -> (kind, 16-token tile)
    int cnts[NK];
    #pragma unroll
    for (int i = 0; i < NK; ++i) cnts[i] = g_counts[i];
    const int bid = blockIdx.x;
    int k = -1, m0 = 0, cum = 0, cnt = 0;
    #pragma unroll
    for (int kk = 0; kk < NK; ++kk) {
        int tk = (cnts[kk] + 15) >> 4;
        if (k < 0 && bid < cum + tk) { k = kk; m0 = (bid - cum) * 16; cnt = cnts[kk]; }
        cum += tk;
    }
    if (k < 0) return;
    const int valid = min(16, cnt - m0);
    const int* buck = g_bucket + (size_t)k * T + m0;

    __shared__ short Hpack[4096];   // h 16x256 bf16 in A-frag order: 8 tiles x 512

    const int tid  = threadIdx.x;
    const int wave = tid >> 6;
    const int lane = tid & 63;
    const int quad = lane >> 4;
    const int cl   = lane & 15;

    // ---- Fourier features directly in A-frag registers (all waves identical):
    // a-frag element j of tile kt: ff[m=cl][kk = kt*32 + quad*8 + j]
    //   kk<24: sin(2*pi*v*B[kk]); kk<48: cos(2*pi*v*B[kk-24]); else 0
    float v = 0.0f;
    if (cl < valid) v = values[buck[cl]];
    s16x8 a0, a1;
    #pragma unroll
    for (int j = 0; j < 8; ++j) {
        // kt=0: quad 0..2 -> sin bands quad*8+j; quad 3 -> cos bands j
        int b0 = (quad == 3) ? j : quad * 8 + j;
        float r0 = __builtin_amdgcn_fractf(v * Bmat[b0]);
        float s0 = __builtin_amdgcn_sinf(r0);
        float c0 = __builtin_amdgcn_cosf(r0);
        a0[j] = pkbf((quad == 3) ? c0 : s0);
        // kt=1: quad 0 -> cos bands 8+j; quad 1 -> cos bands 16+j; quad 2,3 -> 0
        int b1i = min(8 * (quad + 1) + j, 23);
        float r1 = __builtin_amdgcn_fractf(v * Bmat[b1i]);
        float c1 = __builtin_amdgcn_cosf(r1);
        a1[j] = pkbf((quad < 2) ? c1 : 0.0f);
    }

    // ---- GEMM1: [16 x 64] x [64 x 256], wave covers cols [wave*64, +64)
    f32x4 acc[4];
    #pragma unroll
    for (int nt = 0; nt < 4; ++nt) acc[nt] = (f32x4){0.f, 0.f, 0.f, 0.f};
    const s16x8* B1p = (const s16x8*)(g_W1p + (size_t)k * W1PK);
    #pragma unroll
    for (int nt = 0; nt < 4; ++nt)
        acc[nt] = mfma16(a0, B1p[(wave * 4 + nt) * 64 + lane], acc[nt]);
    #pragma unroll
    for (int nt = 0; nt < 4; ++nt)
        acc[nt] = mfma16(a1, B1p[(16 + wave * 4 + nt) * 64 + lane], acc[nt]);

    // ---- bias + GELU -> Hpack (A-frag layout for GEMM2); C-layout source:
    // lane holds H[m=quad*4+r][c=wave*64+nt*16+cl]
    #pragma unroll
    for (int nt = 0; nt < 4; ++nt) {
        int c = wave * 64 + nt * 16 + cl;
        float bias = b1[k * DM + c];
        int kt2 = c >> 5, q2 = (c >> 3) & 3, j2 = c & 7;
        short* hp = Hpack + kt2 * 512 + (q2 << 4) * 8 + j2;
        #pragma unroll
        for (int r = 0; r < 4; ++r) {
            int m = quad * 4 + r;
            float h = gelu_fast(acc[nt][r] + bias);
            hp[m * 8] = pkbf(h);
        }
    }
    __syncthreads();

    // epilogue constants (independent of GEMM2)
    float addc[4];
    #pragma unroll
    for (int nt = 0; nt < 4; ++nt) {
        int c = wave * 64 + nt * 16 + cl;
        addc[nt] = b2[k * DM + c] + kind_emb[k * DM + c];
    }

    // ---- GEMM2: [16 x 256] x [256 x 256], wave covers cols [wave*64, +64)
    f32x4 acc2[4];
    #pragma unroll
    for (int nt = 0; nt < 4; ++nt) acc2[nt] = (f32x4){0.f, 0.f, 0.f, 0.f};
    const s16x8* Hp  = (const s16x8*)Hpack;
    const s16x8* B2p = (const s16x8*)(g_W2p + (size_t)k * W2PK);
    #pragma unroll
    for (int kt = 0; kt < 8; ++kt) {
        s16x8 a = Hp[kt * 64 + lane];
        #pragma unroll
        for (int nt = 0; nt < 4; ++nt)
            acc2[nt] = mfma16(a, B2p[(kt * 16 + wave * 4 + nt) * 64 + lane], acc2[nt]);
    }

    // ---- epilogue: + b2 + kind_emb, scatter rows to out (nontemporal)
    #pragma unroll
    for (int r = 0; r < 4; ++r) {
        int row = quad * 4 + r;
        if (row < valid) {
            size_t ro = (size_t)buck[row] * DM;
            #pragma unroll
            for (int nt = 0; nt < 4; ++nt) {
                int c = wave * 64 + nt * 16 + cl;
                __builtin_nontemporal_store(acc2[nt][r] + addc[nt], out + ro + c);
            }
        }
    }
}

extern "C" void kernel_launch(void* const* d_in, const int* in_sizes, int n_in,
                              void* d_out, int out_size, void* d_ws, size_t ws_size,
                              hipStream_t stream) {
    const float* values   = (const float*)d_in[0];
    const int*   kinds    = (const int*)  d_in[1];
    const float* Bmat     = (const float*)d_in[2];
    const float* kind_emb = (const float*)d_in[3];
    const float* W1       = (const float*)d_in[4];
    const float* b1       = (const float*)d_in[5];
    const float* W2       = (const float*)d_in[6];
    const float* b2       = (const float*)d_in[7];
    float* out = (float*)d_out;
    const int T = in_sizes[0];   // 65536

    prep_kernel<<<dim3(80 + NBLK), dim3(256), 0, stream>>>(W1, W2, kinds, T);
    scatter_kernel<<<dim3(NBLK), dim3(256), 0, stream>>>(kinds, T);
    fproj_gemm<<<dim3(T / 16 + NK), dim3(256), 0, stream>>>(values, Bmat, kind_emb,
                                                            b1, b2, out, T);
}

// Round 6
// 116.274 us; speedup vs baseline: 1.2357x; 1.0548x over previous
//
#include <hip/hip_runtime.h>
#include <hip/hip_bf16.h>
#include <math.h>

// FieldTypedProjector: per-token Fourier features -> per-kind 2-layer MLP (exact GELU)
//   out[t] = W2[k]^T gelu(W1[k]^T ff(v_t) + b1[k]) + b2[k] + kind_emb[k]
// R6: fproj M=32 with R5's structure (FF in A-frag registers, single barrier,
// inline B-frag loads). Rationale: M=16 was L2-BW bound on B re-reads
// (4096 blocks x 160 KB = 640 MB L2 ~ 18.5 us floor); M=32 halves that.
// R4's M=32 was slow due to Apack LDS + 3 barriers + register hoards, all gone here.

#define NK 8
#define DM 256
#define TMAX 65536     // N*S = 32*2048
#define NBLK 256       // T/256 histogram/scatter blocks
#define W1PK 16384     // per-kind packed W1 elements (64*256)
#define W2PK 65536     // per-kind packed W2 elements (256*256)
#define LDSTRIDE 262   // prep slab stride

typedef __attribute__((ext_vector_type(8))) short   s16x8;
typedef __attribute__((ext_vector_type(8))) __bf16  bf16x8;
typedef __attribute__((ext_vector_type(4))) float   f32x4;
typedef __attribute__((ext_vector_type(2))) float   f32x2;
typedef __attribute__((ext_vector_type(4))) int     i32x4;

// Static device scratch — rewritten every call (never touches d_ws).
__device__ int   g_counts[NK];
__device__ __align__(16) int g_blkcnt[NBLK][NK];
__device__ int   g_bucket[(size_t)NK * TMAX];
__device__ __align__(16) short g_W1p[(size_t)NK * W1PK];
__device__ __align__(16) short g_W2p[(size_t)NK * W2PK];

static __device__ __forceinline__ short f2bf(float f) {
    __hip_bfloat16 h = __float2bfloat16(f);
    return __builtin_bit_cast(short, h);
}

// round-to-nearest-ish bf16 truncation (<=1 ulp bf16)
static __device__ __forceinline__ short pkbf(float f) {
    unsigned u = __builtin_bit_cast(unsigned, f);
    return (short)((u + 0x8000u) >> 16);
}

static __device__ __forceinline__ f32x4 mfma16(s16x8 a, s16x8 b, f32x4 c) {
    return __builtin_amdgcn_mfma_f32_16x16x32_bf16(
        __builtin_bit_cast(bf16x8, a), __builtin_bit_cast(bf16x8, b), c, 0, 0, 0);
}

// tanh-form GELU: x*sigmoid(1.59577(x+0.044715x^3)); |err| vs exact erf ~3e-4
static __device__ __forceinline__ float gelu_fast(float x) {
    float t1 = x * x;
    float m  = fmaf(0.0713548162726f, t1, 1.59576912161f);
    float z  = m * x;
    float e  = __expf(-z);
    return x * __frcp_rn(1.0f + e);
}

// ---------------- kernel A: weight pack (LDS-staged) + per-block histograms ---
__global__ __launch_bounds__(256) void prep_kernel(const float* __restrict__ W1,
                                                   const float* __restrict__ W2,
                                                   const int* __restrict__ kinds, int T) {
    __shared__ float ld[32 * LDSTRIDE];
    __shared__ int wcnt[4][NK];
    const int tid = threadIdx.x;
    const int bid = blockIdx.x;
    if (bid < 80) {
        const int isW1 = (bid >= 64);
        int kind, kt;
        if (isW1) { kind = (bid - 64) >> 1; kt = (bid - 64) & 1; }
        else      { kind = bid >> 3;        kt = bid & 7; }
        #pragma unroll
        for (int i = 0; i < 8; ++i) {
            int f = tid + i * 256;
            int row = f >> 6, col = (f & 63) * 4;
            int kk = kt * 32 + row;
            f32x4 v = (f32x4){0.f, 0.f, 0.f, 0.f};
            if (isW1) {
                if (kk < 48) v = *(const f32x4*)(W1 + ((size_t)kind * 48 + kk) * DM + col);
            } else {
                v = *(const f32x4*)(W2 + ((size_t)kind * DM + kk) * DM + col);
            }
            float* dst = &ld[row * LDSTRIDE + col];
            *(f32x2*)dst       = (f32x2){v[0], v[1]};
            *(f32x2*)(dst + 2) = (f32x2){v[2], v[3]};
        }
        __syncthreads();
        short* outp = isW1 ? (g_W1p + (size_t)kind * W1PK) : (g_W2p + (size_t)kind * W2PK);
        #pragma unroll
        for (int i = 0; i < 4; ++i) {
            int g = tid + i * 256;
            int ntile = g >> 6, l = g & 63;
            int kk0 = (l >> 4) * 8, n = ntile * 16 + (l & 15);
            s16x8 v;
            #pragma unroll
            for (int j = 0; j < 8; ++j) v[j] = f2bf(ld[(kk0 + j) * LDSTRIDE + n]);
            *(s16x8*)(outp + ((size_t)(kt * 16 + ntile) * 64 + l) * 8) = v;
        }
    } else {
        const int b = bid - 80;
        const int wave = tid >> 6, lane = tid & 63;
        int t = b * 256 + tid;
        int k = (t < T) ? kinds[t] : -1;
        #pragma unroll
        for (int kk = 0; kk < NK; ++kk) {
            unsigned long long m = __ballot(k == kk);
            if (lane == 0) wcnt[wave][kk] = __popcll(m);
        }
        __syncthreads();
        if (tid < NK) {
            int s = 0;
            #pragma unroll
            for (int w = 0; w < 4; ++w) s += wcnt[w][tid];
            g_blkcnt[b][tid] = s;
        }
    }
}

// ---------------- kernel B: two-level scan over block counts + scatter --------
__global__ __launch_bounds__(256) void scatter_kernel(const int* __restrict__ kinds, int T) {
    __shared__ int cnt_s[NBLK * NK];
    __shared__ int chunksum[32][NK];
    __shared__ int chunkpref[32][NK];
    __shared__ int wcnt[4][NK];
    __shared__ int base_s[NK];
    const int tid = threadIdx.x, wave = tid >> 6, lane = tid & 63;
    const int b = blockIdx.x;
    {
        const i32x4* src = (const i32x4*)&g_blkcnt[0][0];
        i32x4* dst = (i32x4*)cnt_s;
        dst[tid]       = src[tid];
        dst[tid + 256] = src[tid + 256];
    }
    int t = b * 256 + tid;
    int k = (t < T) ? kinds[t] : -1;
    int rank = 0;
    #pragma unroll
    for (int kk = 0; kk < NK; ++kk) {
        unsigned long long m = __ballot(k == kk);
        if (lane == 0) wcnt[wave][kk] = __popcll(m);
        if (k == kk) rank = __popcll(m & ((1ull << lane) - 1ull));
    }
    __syncthreads();
    {
        int kk = tid & 7, ch = tid >> 3;
        int s = 0;
        #pragma unroll
        for (int i = 0; i < 8; ++i) s += cnt_s[(ch * 8 + i) * NK + kk];
        chunksum[ch][kk] = s;
    }
    __syncthreads();
    if (tid < NK) {
        int s = 0;
        #pragma unroll
        for (int ch = 0; ch < 32; ++ch) { chunkpref[ch][tid] = s; s += chunksum[ch][tid]; }
        if (b == 0) g_counts[tid] = s;
        int ch = b >> 3;
        int s2 = chunkpref[ch][tid];
        for (int bb = ch * 8; bb < b; ++bb) s2 += cnt_s[bb * NK + tid];
        base_s[tid] = s2;
        int ws = 0;
        #pragma unroll
        for (int w = 0; w < 4; ++w) { int c = wcnt[w][tid]; wcnt[w][tid] = ws; ws += c; }
    }
    __syncthreads();
    if (k >= 0)
        g_bucket[(size_t)k * T + base_s[k] + wcnt[wave][k] + rank] = t;
}

// ---------------- kernel C: fused MLP, 32-token tile of one kind --------------
__global__ __launch_bounds__(256, 4) void fproj_gemm(
    const float* __restrict__ values, const float* __restrict__ Bmat,
    const float* __restrict__ kind_emb, const float* __restrict__ b1,
    const float* __restrict__ b2, float* __restrict__ out, int T)
{
    // worklist mapping: block -> (kind, 32-token tile)
    int cnts[NK];
    #pragma unroll
    for (int i = 0; i < NK; ++i) cnts[i] = g_counts[i];
    const int bid = blockIdx.x;
    int k = -1, m0 = 0, cum = 0, cnt = 0;
    #pragma unroll
    for (int kk = 0; kk < NK; ++kk) {
        int tk = (cnts[kk] + 31) >> 5;
        if (k < 0 && bid < cum + tk) { k = kk; m0 = (bid - cum) * 32; cnt = cnts[kk]; }
        cum += tk;
    }
    if (k < 0) return;
    const int valid = min(32, cnt - m0);
    const int* buck = g_bucket + (size_t)k * T + m0;

    __shared__ short Hpack[8192];   // h 32x256 bf16, A-frag order: (kt*2+mt)*512 + l*8 + j

    const int tid  = threadIdx.x;
    const int wave = tid >> 6;
    const int lane = tid & 63;
    const int quad = lane >> 4;
    const int cl   = lane & 15;

    // ---- Fourier features directly in A-frag registers for both row groups.
    // a-frag elem j, k-tile kt, row group mt: ff[m = mt*16 + cl][kk = kt*32 + quad*8 + j]
    //   kk<24: sin(2*pi*v*B[kk]); kk<48: cos(2*pi*v*B[kk-24]); else 0
    float vm[2];
    vm[0] = (cl < valid)      ? values[buck[cl]]      : 0.0f;
    vm[1] = (16 + cl < valid) ? values[buck[16 + cl]] : 0.0f;
    s16x8 a0[2], a1[2];
    #pragma unroll
    for (int mt = 0; mt < 2; ++mt) {
        float v = vm[mt];
        #pragma unroll
        for (int j = 0; j < 8; ++j) {
            // kt=0: quad 0..2 -> sin band quad*8+j; quad 3 -> cos band j
            int b0 = (quad == 3) ? j : quad * 8 + j;
            float r0 = __builtin_amdgcn_fractf(v * Bmat[b0]);
            float s0 = __builtin_amdgcn_sinf(r0);
            float c0 = __builtin_amdgcn_cosf(r0);
            a0[mt][j] = pkbf((quad == 3) ? c0 : s0);
            // kt=1: quad 0 -> cos band 8+j; quad 1 -> cos band 16+j; quad 2,3 -> 0
            int b1i = min(8 * (quad + 1) + j, 23);
            float r1 = __builtin_amdgcn_fractf(v * Bmat[b1i]);
            float c1 = __builtin_amdgcn_cosf(r1);
            a1[mt][j] = pkbf((quad < 2) ? c1 : 0.0f);
        }
    }

    // ---- GEMM1: [32 x 64] x [64 x 256], wave covers cols [wave*64, +64)
    f32x4 acc[2][4];
    #pragma unroll
    for (int mt = 0; mt < 2; ++mt)
        #pragma unroll
        for (int nt = 0; nt < 4; ++nt) acc[mt][nt] = (f32x4){0.f, 0.f, 0.f, 0.f};
    const s16x8* B1p = (const s16x8*)(g_W1p + (size_t)k * W1PK);
    #pragma unroll
    for (int kt = 0; kt < 2; ++kt) {
        s16x8 bf[4];
        #pragma unroll
        for (int nt = 0; nt < 4; ++nt) bf[nt] = B1p[(kt * 16 + wave * 4 + nt) * 64 + lane];
        #pragma unroll
        for (int mt = 0; mt < 2; ++mt) {
            s16x8 a = kt ? a1[mt] : a0[mt];
            #pragma unroll
            for (int nt = 0; nt < 4; ++nt) acc[mt][nt] = mfma16(a, bf[nt], acc[mt][nt]);
        }
    }

    // ---- bias + GELU -> Hpack (A-frag layout for GEMM2)
    // C-layout source: lane holds H[m = mt*16 + quad*4 + r][c = wave*64 + nt*16 + cl]
    #pragma unroll
    for (int nt = 0; nt < 4; ++nt) {
        int c = wave * 64 + nt * 16 + cl;
        float bias = b1[k * DM + c];
        int kt2 = c >> 5, q2 = (c >> 3) & 3, j2 = c & 7;
        #pragma unroll
        for (int mt = 0; mt < 2; ++mt) {
            short* hp = Hpack + (kt2 * 2 + mt) * 512 + (q2 << 4) * 8 + j2;
            #pragma unroll
            for (int r = 0; r < 4; ++r) {
                int m = quad * 4 + r;               // row within group
                float h = gelu_fast(acc[mt][nt][r] + bias);
                hp[m * 8] = pkbf(h);
            }
        }
    }
    __syncthreads();

    // epilogue constants (independent of GEMM2)
    float addc[4];
    #pragma unroll
    for (int nt = 0; nt < 4; ++nt) {
        int c = wave * 64 + nt * 16 + cl;
        addc[nt] = b2[k * DM + c] + kind_emb[k * DM + c];
    }

    // ---- GEMM2: [32 x 256] x [256 x 256], wave covers cols [wave*64, +64)
    f32x4 acc2[2][4];
    #pragma unroll
    for (int mt = 0; mt < 2; ++mt)
        #pragma unroll
        for (int nt = 0; nt < 4; ++nt) acc2[mt][nt] = (f32x4){0.f, 0.f, 0.f, 0.f};
    const s16x8* Hp  = (const s16x8*)Hpack;
    const s16x8* B2p = (const s16x8*)(g_W2p + (size_t)k * W2PK);
    #pragma unroll
    for (int kt = 0; kt < 8; ++kt) {
        s16x8 am[2];
        #pragma unroll
        for (int mt = 0; mt < 2; ++mt) am[mt] = Hp[(kt * 2 + mt) * 64 + lane];
        s16x8 bf[4];
        #pragma unroll
        for (int nt = 0; nt < 4; ++nt) bf[nt] = B2p[(kt * 16 + wave * 4 + nt) * 64 + lane];
        #pragma unroll
        for (int mt = 0; mt < 2; ++mt)
            #pragma unroll
            for (int nt = 0; nt < 4; ++nt) acc2[mt][nt] = mfma16(am[mt], bf[nt], acc2[mt][nt]);
    }

    // ---- epilogue: + b2 + kind_emb, scatter rows to out (nontemporal)
    #pragma unroll
    for (int mt = 0; mt < 2; ++mt)
        #pragma unroll
        for (int r = 0; r < 4; ++r) {
            int row = mt * 16 + quad * 4 + r;
            if (row < valid) {
                size_t ro = (size_t)buck[row] * DM;
                #pragma unroll
                for (int nt = 0; nt < 4; ++nt) {
                    int c = wave * 64 + nt * 16 + cl;
                    __builtin_nontemporal_store(acc2[mt][nt][r] + addc[nt], out + ro + c);
                }
            }
        }
}

extern "C" void kernel_launch(void* const* d_in, const int* in_sizes, int n_in,
                              void* d_out, int out_size, void* d_ws, size_t ws_size,
                              hipStream_t stream) {
    const float* values   = (const float*)d_in[0];
    const int*   kinds    = (const int*)  d_in[1];
    const float* Bmat     = (const float*)d_in[2];
    const float* kind_emb = (const float*)d_in[3];
    const float* W1       = (const float*)d_in[4];
    const float* b1       = (const float*)d_in[5];
    const float* W2       = (const float*)d_in[6];
    const float* b2       = (const float*)d_in[7];
    float* out = (float*)d_out;
    const int T = in_sizes[0];   // 65536

    prep_kernel<<<dim3(80 + NBLK), dim3(256), 0, stream>>>(W1, W2, kinds, T);
    scatter_kernel<<<dim3(NBLK), dim3(256), 0, stream>>>(kinds, T);
    fproj_gemm<<<dim3(T / 32 + NK), dim3(256), 0, stream>>>(values, Bmat, kind_emb,
                                                            b1, b2, out, T);
}